// Round 6
// baseline (428.976 us; speedup 1.0000x reference)
//
#include <hip/hip_runtime.h>
#include <math.h>

#define NB 2
#define NL 2048
#define NDIM 1024
#define NH 16
#define ND 64
#define NWS 256
#define NM (NB*NL)
// Q is pre-scaled by log2(e)/8 so attention uses exp2 directly
#define QSCALE 0.18033688011112042f

typedef __attribute__((ext_vector_type(8))) short short8;
typedef __attribute__((ext_vector_type(4))) float f32x4;
typedef unsigned short ushort_t;
typedef unsigned int uint_t;

#define MFMA16(a,b,acc) __builtin_amdgcn_mfma_f32_16x16x32_bf16((a),(b),(acc),0,0,0)

static __device__ __forceinline__ ushort_t f2bf(float x){
    uint_t u = __float_as_uint(x);
    uint_t r = (u + 0x7fff + ((u >> 16) & 1)) >> 16;   // RNE
    return (ushort_t)r;
}
static __device__ __forceinline__ float bf2f(ushort_t u){
    return __uint_as_float(((uint_t)u) << 16);
}
static __device__ __forceinline__ float fast_exp2(float x){
#if __has_builtin(__builtin_amdgcn_exp2f)
    return __builtin_amdgcn_exp2f(x);
#else
    return exp2f(x);
#endif
}

static __device__ __forceinline__ void async_load16(const void* g, void* l){
    __builtin_amdgcn_global_load_lds(
        (const __attribute__((address_space(1))) unsigned int*)g,
        (__attribute__((address_space(3))) unsigned int*)l, 16, 0, 0);
}

// ---------------- fp32 -> bf16 hi/lo split ----------------
__launch_bounds__(256)
__global__ void split_hl(const float* __restrict__ in, ushort_t* __restrict__ oh,
                         ushort_t* __restrict__ ol)
{
    const int i = (blockIdx.x*256 + threadIdx.x)*4;
    const float4 v = *(const float4*)(in + i);
    ushort_t h0=f2bf(v.x), h1=f2bf(v.y), h2=f2bf(v.z), h3=f2bf(v.w);
    ushort4 h4; h4.x=h0; h4.y=h1; h4.z=h2; h4.w=h3;
    ushort4 l4;
    l4.x=f2bf(v.x - bf2f(h0)); l4.y=f2bf(v.y - bf2f(h1));
    l4.z=f2bf(v.z - bf2f(h2)); l4.w=f2bf(v.w - bf2f(h3));
    *(ushort4*)(oh + i) = h4;
    *(ushort4*)(ol + i) = l4;
}

// ---------------- rope cos/sin tables [j][l], j<32 ----------------
__launch_bounds__(256)
__global__ void rope_tab(float* __restrict__ tc, float* __restrict__ ts)
{
    const int idx = blockIdx.x*256 + threadIdx.x;   // 32*2048
    const int j = idx >> 11, l = idx & (NL-1);
    const float invf = 1.0f / powf(10000.0f, (float)j * (1.0f/32.0f));
    float s, c;
    sincosf((float)l * invf, &s, &c);
    tc[idx] = c; ts[idx] = s;
}

// ---------------- bf16 hi/lo MFMA GEMM ----------------
// MODE 0: QKV gemm (2-term: ah*bh + al*bh) — fused RoPE, Q (pre-scaled)/K -> [B,H,L,D],
//         V -> transposed [B,H,D,L].  B-lo neither staged nor read.
// MODE 1: proj gemm (3-term hi/lo) — fp32 row-major C
template<int MODE>
__launch_bounds__(256, 2)
__global__ void gemm_hl(const ushort_t* __restrict__ Ah, const ushort_t* __restrict__ Al,
                        const ushort_t* __restrict__ Bh, const ushort_t* __restrict__ Bl,
                        const float* __restrict__ bias,
                        float* __restrict__ Cout,
                        ushort_t* __restrict__ oQh, ushort_t* __restrict__ oQl,
                        ushort_t* __restrict__ oKh,
                        ushort_t* __restrict__ oVth, ushort_t* __restrict__ oVtl,
                        const float* __restrict__ tcos, const float* __restrict__ tsin)
{
    __shared__ __align__(16) ushort_t sA_h[128*32];
    __shared__ __align__(16) ushort_t sA_l[128*32];
    __shared__ __align__(16) ushort_t sB_h[128*32];
    __shared__ __align__(16) ushort_t sB_l[(MODE==1) ? 128*32 : 8];
    __shared__ __align__(16) ushort_t sBounce[(MODE==0) ? 4*64*72 : 8];

    const int tid  = threadIdx.x;
    const int wv   = tid >> 6, lane = tid & 63;
    const int quad = lane >> 4, l16 = lane & 15;
    const int m0 = blockIdx.y << 7, n0 = blockIdx.x << 7;
    const int wr = wv >> 1, wc = wv & 1;

    // staging assignment
    const ushort_t* gsrc;
    ushort_t* lds_base;
    int rowb, npass;
    if (MODE == 1) {
        gsrc = (wv==0)?Ah:(wv==1)?Al:(wv==2)?Bh:Bl;
        lds_base = (wv==0)?sA_h:(wv==1)?sA_l:(wv==2)?sB_h:sB_l;
        rowb = (wv < 2) ? m0 : n0;
        npass = 8;
    } else {
        // 0:A_h (8 passes) 1:A_l (8) 2:B_h rows0-63 (4) 3:B_h rows64-127 (4)
        if (wv == 0)      { gsrc = Ah; lds_base = sA_h; rowb = m0; npass = 8; }
        else if (wv == 1) { gsrc = Al; lds_base = sA_l; rowb = m0; npass = 8; }
        else { gsrc = Bh; lds_base = sB_h + (wv-2)*64*32; rowb = n0 + (wv-2)*64; npass = 4; }
    }
    const int rl = lane >> 2;
    const int cp = lane & 3;
    const int cg = cp ^ ((rl >> 1) & 3);
    const ushort_t* gptr = gsrc + (size_t)(rowb + rl)*NDIM + cg*8;

    f32x4 acc[4][4];
    #pragma unroll
    for (int i=0;i<4;++i)
        #pragma unroll
        for (int j=0;j<4;++j) acc[i][j] = (f32x4){0.f,0.f,0.f,0.f};

    const int swz = (l16 >> 1) & 3;
    const int ac_off = (wr*64 + l16)*32 + ((quad ^ swz) << 3);
    const int bc_off = (wc*64 + l16)*32 + ((quad ^ swz) << 3);

    for (int k0 = 0; k0 < NDIM; k0 += 32) {
        __syncthreads();
        const ushort_t* gp = gptr + k0;
        for (int p=0; p<npass; ++p)
            async_load16(gp + (size_t)p*16*NDIM, (char*)lds_base + p*1024);
        __syncthreads();

        short8 ah[4], al[4], bh[4], bl[4];
        #pragma unroll
        for (int t=0;t<4;++t){
            ah[t] = *(const short8*)&sA_h[t*512 + ac_off];
            al[t] = *(const short8*)&sA_l[t*512 + ac_off];
            bh[t] = *(const short8*)&sB_h[t*512 + bc_off];
            if (MODE == 1) bl[t] = *(const short8*)&sB_l[t*512 + bc_off];
        }
        #pragma unroll
        for (int mt=0;mt<4;++mt)
            #pragma unroll
            for (int nt=0;nt<4;++nt){
                f32x4 a = acc[mt][nt];
                a = MFMA16(ah[mt], bh[nt], a);
                a = MFMA16(al[mt], bh[nt], a);
                if (MODE == 1) a = MFMA16(ah[mt], bl[nt], a);
                acc[mt][nt] = a;
            }
    }

    if (MODE == 1) {
        const int colb = n0 + wc*64;
        float bq[4];
        #pragma unroll
        for (int nt=0;nt<4;++nt) bq[nt] = bias[colb + nt*16 + l16];
        #pragma unroll
        for (int mt=0;mt<4;++mt)
            #pragma unroll
            for (int r=0;r<4;++r){
                const int m = m0 + wr*64 + mt*16 + quad*4 + r;
                float* orow = Cout + (size_t)m*NDIM + colb;
                #pragma unroll
                for (int nt=0;nt<4;++nt)
                    orow[nt*16 + l16] = acc[mt][nt][r] + bq[nt];
            }
    } else {
        const int colb = n0 + wc*64;          // 64-aligned -> single (sel, head)
        const int sel  = colb >> 10;          // 0:q 1:k 2:v
        const int head = (colb & 1023) >> 6;
        float bq[4];
        #pragma unroll
        for (int nt=0;nt<4;++nt) bq[nt] = bias[colb + nt*16 + l16];

        if (sel == 2) {
            // V -> transposed global [B,H,D,L] via per-wave LDS bounce
            const int bb = m0 >> 11;
            const int Lb = (m0 & (NL-1)) + wr*64;
            ushort_t* sT = sBounce + wv*(64*72);
            const size_t gb = ((size_t)(bb*NH + head)*ND)*NL + Lb;
            const int drow = lane >> 3, dcol = lane & 7;
            #pragma unroll
            for (int pass=0; pass<2; ++pass){
                #pragma unroll
                for (int mt=0;mt<4;++mt)
                    #pragma unroll
                    for (int nt=0;nt<4;++nt)
                        #pragma unroll
                        for (int r=0;r<4;++r){
                            const float val = acc[mt][nt][r] + bq[nt];
                            const ushort_t h = f2bf(val);
                            const ushort_t w = pass ? f2bf(val - bf2f(h)) : h;
                            sT[(nt*16+l16)*72 + mt*16 + quad*4 + r] = w;
                        }
                ushort_t* gdst = pass ? oVtl : oVth;
                #pragma unroll
                for (int dd=0; dd<8; ++dd){
                    const int d = dd*8 + drow;
                    const uint4 v = *(const uint4*)&sT[d*72 + dcol*8];
                    *(uint4*)(gdst + gb + (size_t)d*NL + dcol*8) = v;
                }
            }
        } else {
            ushort_t* dh = sel ? oKh : oQh;
            const float qs = sel ? 1.0f : QSCALE;
            #pragma unroll
            for (int mt=0;mt<4;++mt)
                #pragma unroll
                for (int r=0;r<4;++r){
                    const int m = m0 + wr*64 + mt*16 + quad*4 + r;
                    const int bb = m >> 11, l = m & (NL-1);
                    const size_t ro = ((size_t)((bb*NH + head)*NL + l)) << 6;
                    #pragma unroll
                    for (int ntp=0;ntp<2;++ntp){
                        const int j = ntp*16 + l16;
                        const float c = tcos[j*NL + l];
                        const float s = tsin[j*NL + l];
                        const float x1 = acc[mt][ntp  ][r] + bq[ntp];
                        const float x2 = acc[mt][ntp+2][r] + bq[ntp+2];
                        const float ra = (x1*c - x2*s) * qs;
                        const float rb = (x2*c + x1*s) * qs;
                        const int d1 = ntp*16 + l16;
                        ushort_t h;
                        h = f2bf(ra); dh[ro + d1] = h;
                        if (sel == 0) oQl[ro + d1] = f2bf(ra - bf2f(h));
                        h = f2bf(rb); dh[ro + d1 + 32] = h;
                        if (sel == 0) oQl[ro + d1 + 32] = f2bf(rb - bf2f(h));
                    }
                }
        }
    }
}

// ---------------- MFMA flash attention: K-split, barrier-light ----------------
// block = 512 thr = 8 waves: 4 q-subtiles (32 q) x 2 K-halves. Flat softmax ->
// partial (O, l) combine by simple addition through LDS. K/V frags from global.
__launch_bounds__(512, 4)
__global__ void attn_mfma(const ushort_t* __restrict__ Qh, const ushort_t* __restrict__ Ql,
                          const ushort_t* __restrict__ Kh,
                          const ushort_t* __restrict__ Vth, const ushort_t* __restrict__ Vtl,
                          ushort_t* __restrict__ AOh, ushort_t* __restrict__ AOl,
                          const int* __restrict__ isg)
{
    __shared__ __align__(16) ushort_t sP[8][32*68];   // per-wave P (bf16), [q][key]
    __shared__ __align__(16) float    sO[4][32*66];   // kh=1 partial O
    __shared__ float sLs[4][32];

    const int tid  = threadIdx.x;
    const int wv   = tid >> 6, lane = tid & 63;
    const int qg   = wv & 3, kh = wv >> 2;
    const int quad = lane >> 4, l16 = lane & 15;
    const int bh = blockIdx.x & 31, qt = blockIdx.x >> 5;   // XCD-local bh
    const int q0 = qt*128 + qg*32;
    ushort_t* sPw = sP[wv];

    // Q B-frags (n=query on l16, k=d); Q pre-scaled by log2e/8
    short8 bqh[2][2], bql[2][2];
    {
        const size_t rb = ((size_t)bh*NL + q0) << 6;
        #pragma unroll
        for (int mt=0; mt<2; ++mt)
            #pragma unroll
            for (int c=0; c<2; ++c) {
                const size_t off = rb + (size_t)((mt*16 + l16) << 6) + quad*8 + c*32;
                bqh[mt][c] = *(const short8*)(Qh + off);
                bql[mt][c] = *(const short8*)(Ql + off);
            }
    }

    f32x4 o[2][4];
    #pragma unroll
    for (int mt=0; mt<2; ++mt)
        #pragma unroll
        for (int dnt=0; dnt<4; ++dnt)
            o[mt][dnt] = (f32x4){0.f,0.f,0.f,0.f};
    f32x4 ls4[2] = {(f32x4){0.f,0.f,0.f,0.f}, (f32x4){0.f,0.f,0.f,0.f}};

    const int gflag = isg[0];
    int klo, khi;
    if (gflag) { klo = kh*(NL/2); khi = klo + NL/2; }
    else       { const int wb = (qt >> 1)*NWS; klo = wb + kh*(NWS/2); khi = klo + NWS/2; }
    const size_t kvbase = ((size_t)bh*NL) << 6;   // K rows [key][d]
    const size_t vtbase = ((size_t)bh*ND)*NL;     // V^T rows [d][key]

    for (int kt = klo; kt < khi; kt += 64) {
        // ---- K A-frags direct from global ----
        short8 akh[4][2];
        #pragma unroll
        for (int knt=0; knt<4; ++knt) {
            const size_t kr = kvbase + ((size_t)(kt + knt*16 + l16) << 6) + quad*8;
            akh[knt][0] = *(const short8*)(Kh + kr);
            akh[knt][1] = *(const short8*)(Kh + kr + 32);
        }

        // ---- S^T = K Q^T (log2-domain) : rows=key(quad*4+r), cols=query(l16) ----
        f32x4 s[2][4];
        #pragma unroll
        for (int mt=0; mt<2; ++mt)
            #pragma unroll
            for (int knt=0; knt<4; ++knt) {
                f32x4 a = (f32x4){0.f,0.f,0.f,0.f};
                a = MFMA16(akh[knt][0], bqh[mt][0], a);
                a = MFMA16(akh[knt][1], bqh[mt][1], a);
                a = MFMA16(akh[knt][0], bql[mt][0], a);
                a = MFMA16(akh[knt][1], bql[mt][1], a);
                s[mt][knt] = a;
            }

        // ---- p = exp2(s), truncate to bf16, accumulate ls (4-wide), store sP ----
        #pragma unroll
        for (int mt=0; mt<2; ++mt)
            #pragma unroll
            for (int knt=0; knt<4; ++knt) {
                uint_t u[4];
                #pragma unroll
                for (int r=0;r<4;++r) {
                    const float p = fast_exp2(s[mt][knt][r]);
                    const uint_t pu = __float_as_uint(p) & 0xffff0000u;
                    ls4[mt][r] += __uint_as_float(pu);
                    u[r] = pu;
                }
                uint2 pk;
                pk.x = __builtin_amdgcn_perm(u[1], u[0], 0x07060302u);
                pk.y = __builtin_amdgcn_perm(u[3], u[2], 0x07060302u);
                *(uint2*)&sPw[(mt*16 + l16)*68 + knt*16 + quad*4] = pk;
            }

        // ---- P A-frags (stored as bf16, no unpack) ----
        short8 fp[2][2];
        #pragma unroll
        for (int mt=0; mt<2; ++mt)
            #pragma unroll
            for (int c=0; c<2; ++c)
                fp[mt][c] = *(const short8*)&sPw[(mt*16 + l16)*68 + c*32 + quad*8];

        // ---- PV: O += P (Vh + Vl), V^T B-frags from global ----
        #pragma unroll
        for (int dnt=0; dnt<4; ++dnt) {
            const size_t vg = vtbase + (size_t)(dnt*16 + l16)*NL + kt + quad*8;
            const short8 vh0 = *(const short8*)(Vth + vg);
            const short8 vh1 = *(const short8*)(Vth + vg + 32);
            const short8 vl0 = *(const short8*)(Vtl + vg);
            const short8 vl1 = *(const short8*)(Vtl + vg + 32);
            #pragma unroll
            for (int mt=0; mt<2; ++mt) {
                f32x4 a = o[mt][dnt];
                a = MFMA16(fp[mt][0], vh0, a);
                a = MFMA16(fp[mt][1], vh1, a);
                a = MFMA16(fp[mt][0], vl0, a);
                a = MFMA16(fp[mt][1], vl1, a);
                o[mt][dnt] = a;
            }
        }
    }

    // ---- reduce ls within wave (keys split over quads and the r lanes) ----
    float ls[2];
    #pragma unroll
    for (int mt=0; mt<2; ++mt) {
        float t = (ls4[mt][0] + ls4[mt][1]) + (ls4[mt][2] + ls4[mt][3]);
        t += __shfl_xor(t, 16);
        t += __shfl_xor(t, 32);
        ls[mt] = t;             // per-query sum, indexed by l16, replicated
    }

    // ---- cross-half combine: kh=1 dumps partials, kh=0 adds ----
    if (kh == 1) {
        #pragma unroll
        for (int mt=0; mt<2; ++mt) {
            if (quad == 0) sLs[qg][mt*16 + l16] = ls[mt];
            #pragma unroll
            for (int r=0; r<4; ++r) {
                const int row = mt*16 + quad*4 + r;
                #pragma unroll
                for (int dnt=0; dnt<4; ++dnt)
                    sO[qg][row*66 + dnt*16 + l16] = o[mt][dnt][r];
            }
        }
    }
    __syncthreads();
    if (kh == 0) {
        #pragma unroll
        for (int mt=0; mt<2; ++mt) {
            ls[mt] += sLs[qg][mt*16 + l16];
            #pragma unroll
            for (int r=0; r<4; ++r) {
                const int row = mt*16 + quad*4 + r;
                #pragma unroll
                for (int dnt=0; dnt<4; ++dnt)
                    o[mt][dnt][r] += sO[qg][row*66 + dnt*16 + l16];
            }
        }

        // ---- epilogue: O rows = quad*4+r; fetch ls from matching l16 lane ----
        const int bb = bh >> 4, hh = bh & 15;
        #pragma unroll
        for (int mt=0; mt<2; ++mt)
            #pragma unroll
            for (int r=0; r<4; ++r) {
                const float lsv = __int_as_float(__builtin_amdgcn_ds_bpermute(
                    (quad*4 + r) << 2, __float_as_int(ls[mt])));
                const float inv = 1.0f / lsv;
                const int row = q0 + mt*16 + quad*4 + r;
                const size_t ob = (((size_t)(bb*NL + row)) << 10) + (hh << 6);
                #pragma unroll
                for (int dnt=0; dnt<4; ++dnt) {
                    const float val = o[mt][dnt][r] * inv;
                    const ushort_t h = f2bf(val);
                    AOh[ob + dnt*16 + l16] = h;
                    AOl[ob + dnt*16 + l16] = f2bf(val - bf2f(h));
                }
            }
    }
}

extern "C" void kernel_launch(void* const* d_in, const int* in_sizes, int n_in,
                              void* d_out, int out_size, void* d_ws, size_t ws_size,
                              hipStream_t stream)
{
    const float* x     = (const float*)d_in[0];
    const float* Wqkv  = (const float*)d_in[1];
    const float* bqkv  = (const float*)d_in[2];
    const float* Wproj = (const float*)d_in[3];
    const float* bproj = (const float*)d_in[4];
    const int*   isg   = (const int*)d_in[5];
    float* out = (float*)d_out;
    char* base = (char*)d_ws;

    const size_t MB = 1024*1024;
    ushort_t* Qh  = (ushort_t*)(base);
    ushort_t* Ql  = (ushort_t*)(base + 8*MB);
    ushort_t* Kh  = (ushort_t*)(base + 16*MB);
    ushort_t* Vth = (ushort_t*)(base + 32*MB);
    ushort_t* Vtl = (ushort_t*)(base + 40*MB);
    ushort_t* xh  = (ushort_t*)(base + 48*MB);
    ushort_t* xl  = (ushort_t*)(base + 56*MB);
    ushort_t* AOh = xh;                       // alias: xh dead after gemm1
    ushort_t* AOl = xl;
    ushort_t* Wqh = (ushort_t*)(base + 64*MB);
    ushort_t* Wql = (ushort_t*)(base + 64*MB + 6291456);
    ushort_t* Wph = (ushort_t*)(base + 76*MB);
    ushort_t* Wpl = (ushort_t*)(base + 76*MB + 2097152);
    float*    tcs = (float*)(base + 80*MB);          // 32*2048 f32
    float*    tsn = (float*)(base + 80*MB + 262144);

    split_hl<<<4096, 256, 0, stream>>>(x, xh, xl);
    split_hl<<<3072, 256, 0, stream>>>(Wqkv, Wqh, Wql);
    split_hl<<<1024, 256, 0, stream>>>(Wproj, Wph, Wpl);
    rope_tab<<<256, 256, 0, stream>>>(tcs, tsn);

    gemm_hl<0><<<dim3(3*NDIM/128, NM/128), 256, 0, stream>>>(
        xh, xl, Wqh, Wql, bqkv, nullptr,
        Qh, Ql, Kh, Vth, Vtl, tcs, tsn);

    attn_mfma<<<NB*NH*(NL/128), 512, 0, stream>>>(
        Qh, Ql, Kh, Vth, Vtl, AOh, AOl, isg);

    gemm_hl<1><<<dim3(NDIM/128, NM/128), 256, 0, stream>>>(
        AOh, AOl, Wph, Wpl, bproj, out,
        nullptr, nullptr, nullptr, nullptr, nullptr, nullptr, nullptr);
}

// Round 7
// 327.036 us; speedup vs baseline: 1.3117x; 1.3117x over previous
//
#include <hip/hip_runtime.h>
#include <math.h>

#define NB 2
#define NL 2048
#define NDIM 1024
#define NH 16
#define ND 64
#define NWS 256
#define NM (NB*NL)
// Q is pre-scaled by log2(e)/8 so attention uses exp2 directly
#define QSCALE 0.18033688011112042f

typedef __attribute__((ext_vector_type(8))) short short8;
typedef __attribute__((ext_vector_type(4))) float f32x4;
typedef unsigned short ushort_t;
typedef unsigned int uint_t;

#define MFMA16(a,b,acc) __builtin_amdgcn_mfma_f32_16x16x32_bf16((a),(b),(acc),0,0,0)

static __device__ __forceinline__ ushort_t f2bf(float x){
    uint_t u = __float_as_uint(x);
    uint_t r = (u + 0x7fff + ((u >> 16) & 1)) >> 16;   // RNE
    return (ushort_t)r;
}
static __device__ __forceinline__ float bf2f(ushort_t u){
    return __uint_as_float(((uint_t)u) << 16);
}
static __device__ __forceinline__ float fast_exp2(float x){
#if __has_builtin(__builtin_amdgcn_exp2f)
    return __builtin_amdgcn_exp2f(x);
#else
    return exp2f(x);
#endif
}

static __device__ __forceinline__ void async_load16(const void* g, void* l){
    __builtin_amdgcn_global_load_lds(
        (const __attribute__((address_space(1))) unsigned int*)g,
        (__attribute__((address_space(3))) unsigned int*)l, 16, 0, 0);
}

// ---------------- fp32 -> bf16 hi/lo split ----------------
__launch_bounds__(256)
__global__ void split_hl(const float* __restrict__ in, ushort_t* __restrict__ oh,
                         ushort_t* __restrict__ ol)
{
    const int i = (blockIdx.x*256 + threadIdx.x)*4;
    const float4 v = *(const float4*)(in + i);
    ushort_t h0=f2bf(v.x), h1=f2bf(v.y), h2=f2bf(v.z), h3=f2bf(v.w);
    ushort4 h4; h4.x=h0; h4.y=h1; h4.z=h2; h4.w=h3;
    ushort4 l4;
    l4.x=f2bf(v.x - bf2f(h0)); l4.y=f2bf(v.y - bf2f(h1));
    l4.z=f2bf(v.z - bf2f(h2)); l4.w=f2bf(v.w - bf2f(h3));
    *(ushort4*)(oh + i) = h4;
    *(ushort4*)(ol + i) = l4;
}

// ---------------- rope cos/sin tables [j][l], j<32 ----------------
__launch_bounds__(256)
__global__ void rope_tab(float* __restrict__ tc, float* __restrict__ ts)
{
    const int idx = blockIdx.x*256 + threadIdx.x;   // 32*2048
    const int j = idx >> 11, l = idx & (NL-1);
    const float invf = 1.0f / powf(10000.0f, (float)j * (1.0f/32.0f));
    float s, c;
    sincosf((float)l * invf, &s, &c);
    tc[idx] = c; ts[idx] = s;
}

// ---------------- bf16 hi/lo MFMA GEMM ----------------
// MODE 0: QKV gemm (2-term: ah*bh + al*bh) — fused RoPE, Q (pre-scaled)/K bf16-only
//         -> [B,H,L,D], V -> transposed bf16-only [B,H,D,L]
// MODE 1: proj gemm (3-term hi/lo) — fp32 row-major C
template<int MODE>
__launch_bounds__(256, 2)
__global__ void gemm_hl(const ushort_t* __restrict__ Ah, const ushort_t* __restrict__ Al,
                        const ushort_t* __restrict__ Bh, const ushort_t* __restrict__ Bl,
                        const float* __restrict__ bias,
                        float* __restrict__ Cout,
                        ushort_t* __restrict__ oQh, ushort_t* __restrict__ oKh,
                        ushort_t* __restrict__ oVth,
                        const float* __restrict__ tcos, const float* __restrict__ tsin)
{
    __shared__ __align__(16) ushort_t sA_h[128*32];
    __shared__ __align__(16) ushort_t sA_l[128*32];
    __shared__ __align__(16) ushort_t sB_h[128*32];
    __shared__ __align__(16) ushort_t sB_l[(MODE==1) ? 128*32 : 8];
    __shared__ __align__(16) ushort_t sBounce[(MODE==0) ? 4*64*72 : 8];

    const int tid  = threadIdx.x;
    const int wv   = tid >> 6, lane = tid & 63;
    const int quad = lane >> 4, l16 = lane & 15;
    const int m0 = blockIdx.y << 7, n0 = blockIdx.x << 7;
    const int wr = wv >> 1, wc = wv & 1;

    // staging assignment
    const ushort_t* gsrc;
    ushort_t* lds_base;
    int rowb, npass;
    if (MODE == 1) {
        gsrc = (wv==0)?Ah:(wv==1)?Al:(wv==2)?Bh:Bl;
        lds_base = (wv==0)?sA_h:(wv==1)?sA_l:(wv==2)?sB_h:sB_l;
        rowb = (wv < 2) ? m0 : n0;
        npass = 8;
    } else {
        // 0:A_h (8 passes) 1:A_l (8) 2:B_h rows0-63 (4) 3:B_h rows64-127 (4)
        if (wv == 0)      { gsrc = Ah; lds_base = sA_h; rowb = m0; npass = 8; }
        else if (wv == 1) { gsrc = Al; lds_base = sA_l; rowb = m0; npass = 8; }
        else { gsrc = Bh; lds_base = sB_h + (wv-2)*64*32; rowb = n0 + (wv-2)*64; npass = 4; }
    }
    const int rl = lane >> 2;
    const int cp = lane & 3;
    const int cg = cp ^ ((rl >> 1) & 3);
    const ushort_t* gptr = gsrc + (size_t)(rowb + rl)*NDIM + cg*8;

    f32x4 acc[4][4];
    #pragma unroll
    for (int i=0;i<4;++i)
        #pragma unroll
        for (int j=0;j<4;++j) acc[i][j] = (f32x4){0.f,0.f,0.f,0.f};

    const int swz = (l16 >> 1) & 3;
    const int ac_off = (wr*64 + l16)*32 + ((quad ^ swz) << 3);
    const int bc_off = (wc*64 + l16)*32 + ((quad ^ swz) << 3);

    for (int k0 = 0; k0 < NDIM; k0 += 32) {
        __syncthreads();
        const ushort_t* gp = gptr + k0;
        for (int p=0; p<npass; ++p)
            async_load16(gp + (size_t)p*16*NDIM, (char*)lds_base + p*1024);
        __syncthreads();

        short8 ah[4], al[4], bh[4], bl[4];
        #pragma unroll
        for (int t=0;t<4;++t){
            ah[t] = *(const short8*)&sA_h[t*512 + ac_off];
            al[t] = *(const short8*)&sA_l[t*512 + ac_off];
            bh[t] = *(const short8*)&sB_h[t*512 + bc_off];
            if (MODE == 1) bl[t] = *(const short8*)&sB_l[t*512 + bc_off];
        }
        #pragma unroll
        for (int mt=0;mt<4;++mt)
            #pragma unroll
            for (int nt=0;nt<4;++nt){
                f32x4 a = acc[mt][nt];
                a = MFMA16(ah[mt], bh[nt], a);
                a = MFMA16(al[mt], bh[nt], a);
                if (MODE == 1) a = MFMA16(ah[mt], bl[nt], a);
                acc[mt][nt] = a;
            }
    }

    if (MODE == 1) {
        const int colb = n0 + wc*64;
        float bq[4];
        #pragma unroll
        for (int nt=0;nt<4;++nt) bq[nt] = bias[colb + nt*16 + l16];
        #pragma unroll
        for (int mt=0;mt<4;++mt)
            #pragma unroll
            for (int r=0;r<4;++r){
                const int m = m0 + wr*64 + mt*16 + quad*4 + r;
                float* orow = Cout + (size_t)m*NDIM + colb;
                #pragma unroll
                for (int nt=0;nt<4;++nt)
                    orow[nt*16 + l16] = acc[mt][nt][r] + bq[nt];
            }
    } else {
        const int colb = n0 + wc*64;          // 64-aligned -> single (sel, head)
        const int sel  = colb >> 10;          // 0:q 1:k 2:v
        const int head = (colb & 1023) >> 6;
        float bq[4];
        #pragma unroll
        for (int nt=0;nt<4;++nt) bq[nt] = bias[colb + nt*16 + l16];

        if (sel == 2) {
            // V -> transposed global [B,H,D,L] (bf16 only) via per-wave LDS bounce
            const int bb = m0 >> 11;
            const int Lb = (m0 & (NL-1)) + wr*64;
            ushort_t* sT = sBounce + wv*(64*72);
            const size_t gb = ((size_t)(bb*NH + head)*ND)*NL + Lb;
            const int drow = lane >> 3, dcol = lane & 7;
            #pragma unroll
            for (int mt=0;mt<4;++mt)
                #pragma unroll
                for (int nt=0;nt<4;++nt)
                    #pragma unroll
                    for (int r=0;r<4;++r)
                        sT[(nt*16+l16)*72 + mt*16 + quad*4 + r] = f2bf(acc[mt][nt][r] + bq[nt]);
            #pragma unroll
            for (int dd=0; dd<8; ++dd){
                const int d = dd*8 + drow;
                const uint4 v = *(const uint4*)&sT[d*72 + dcol*8];
                *(uint4*)(oVth + gb + (size_t)d*NL + dcol*8) = v;
            }
        } else {
            ushort_t* dh = sel ? oKh : oQh;
            const float qs = sel ? 1.0f : QSCALE;
            #pragma unroll
            for (int mt=0;mt<4;++mt)
                #pragma unroll
                for (int r=0;r<4;++r){
                    const int m = m0 + wr*64 + mt*16 + quad*4 + r;
                    const int bb = m >> 11, l = m & (NL-1);
                    const size_t ro = ((size_t)((bb*NH + head)*NL + l)) << 6;
                    #pragma unroll
                    for (int ntp=0;ntp<2;++ntp){
                        const int j = ntp*16 + l16;
                        const float c = tcos[j*NL + l];
                        const float s = tsin[j*NL + l];
                        const float x1 = acc[mt][ntp  ][r] + bq[ntp];
                        const float x2 = acc[mt][ntp+2][r] + bq[ntp+2];
                        const int d1 = ntp*16 + l16;
                        dh[ro + d1]      = f2bf((x1*c - x2*s) * qs);
                        dh[ro + d1 + 32] = f2bf((x2*c + x1*s) * qs);
                    }
                }
        }
    }
}

// ---------------- MFMA flash attention: K-split, pure bf16, barrier-light ----------------
// block = 256 thr = 4 waves: 2 q-subtiles (32 q) x 2 K-halves. Flat softmax ->
// partial (O, l) combine by simple addition through LDS. K/V frags from global.
__launch_bounds__(256, 4)
__global__ void attn_mfma(const ushort_t* __restrict__ Qh,
                          const ushort_t* __restrict__ Kh,
                          const ushort_t* __restrict__ Vth,
                          ushort_t* __restrict__ AOh, ushort_t* __restrict__ AOl,
                          const int* __restrict__ isg)
{
    __shared__ __align__(16) ushort_t sP[4][32*68];   // per-wave P (bf16), [q][key]
    __shared__ __align__(16) float    sO[2][32*66];   // kh=1 partial O per q-subtile
    __shared__ float sLs[2][32];

    const int tid  = threadIdx.x;
    const int wv   = tid >> 6, lane = tid & 63;
    const int qg   = wv & 1, kh = wv >> 1;
    const int quad = lane >> 4, l16 = lane & 15;
    const int bh = blockIdx.x & 31, qt = blockIdx.x >> 5;   // XCD-local bh; qt 0..31
    const int q0 = qt*64 + qg*32;
    ushort_t* sPw = sP[wv];

    // Q B-frags (n=query on l16, k=d); Q pre-scaled by log2e/8
    short8 bq[2][2];
    {
        const size_t rb = ((size_t)bh*NL + q0) << 6;
        #pragma unroll
        for (int mt=0; mt<2; ++mt)
            #pragma unroll
            for (int c=0; c<2; ++c)
                bq[mt][c] = *(const short8*)(Qh + rb + (size_t)((mt*16 + l16) << 6) + quad*8 + c*32);
    }

    f32x4 o[2][4];
    #pragma unroll
    for (int mt=0; mt<2; ++mt)
        #pragma unroll
        for (int dnt=0; dnt<4; ++dnt)
            o[mt][dnt] = (f32x4){0.f,0.f,0.f,0.f};
    f32x4 ls4[2] = {(f32x4){0.f,0.f,0.f,0.f}, (f32x4){0.f,0.f,0.f,0.f}};

    const int gflag = isg[0];
    int klo, khi;
    if (gflag) { klo = kh*(NL/2); khi = klo + NL/2; }                       // 16 tiles
    else       { const int wb = (qt >> 2)*NWS; klo = wb + kh*(NWS/2); khi = klo + NWS/2; } // 2
    const size_t kvbase = ((size_t)bh*NL) << 6;   // K rows [key][d]
    const size_t vtbase = ((size_t)bh*ND)*NL;     // V^T rows [d][key]

    for (int kt = klo; kt < khi; kt += 64) {
        // ---- K A-frags direct from global ----
        short8 ak[4][2];
        #pragma unroll
        for (int knt=0; knt<4; ++knt) {
            const size_t kr = kvbase + ((size_t)(kt + knt*16 + l16) << 6) + quad*8;
            ak[knt][0] = *(const short8*)(Kh + kr);
            ak[knt][1] = *(const short8*)(Kh + kr + 32);
        }

        // ---- S^T = K Q^T (log2-domain) : rows=key(quad*4+r), cols=query(l16) ----
        f32x4 s[2][4];
        #pragma unroll
        for (int mt=0; mt<2; ++mt)
            #pragma unroll
            for (int knt=0; knt<4; ++knt) {
                f32x4 a = (f32x4){0.f,0.f,0.f,0.f};
                a = MFMA16(ak[knt][0], bq[mt][0], a);
                a = MFMA16(ak[knt][1], bq[mt][1], a);
                s[mt][knt] = a;
            }

        // ---- p = exp2(s), truncate to bf16, accumulate ls (4-wide), store sP ----
        #pragma unroll
        for (int mt=0; mt<2; ++mt)
            #pragma unroll
            for (int knt=0; knt<4; ++knt) {
                uint_t u[4];
                #pragma unroll
                for (int r=0;r<4;++r) {
                    const float p = fast_exp2(s[mt][knt][r]);
                    const uint_t pu = __float_as_uint(p) & 0xffff0000u;
                    ls4[mt][r] += __uint_as_float(pu);
                    u[r] = pu;
                }
                uint2 pk;
                pk.x = __builtin_amdgcn_perm(u[1], u[0], 0x07060302u);
                pk.y = __builtin_amdgcn_perm(u[3], u[2], 0x07060302u);
                *(uint2*)&sPw[(mt*16 + l16)*68 + knt*16 + quad*4] = pk;
            }

        // ---- P A-frags (stored as bf16, no unpack) ----
        short8 fp[2][2];
        #pragma unroll
        for (int mt=0; mt<2; ++mt)
            #pragma unroll
            for (int c=0; c<2; ++c)
                fp[mt][c] = *(const short8*)&sPw[(mt*16 + l16)*68 + c*32 + quad*8];

        // ---- PV: O += P V, V^T B-frags from global (bf16 only) ----
        #pragma unroll
        for (int dnt=0; dnt<4; ++dnt) {
            const size_t vg = vtbase + (size_t)(dnt*16 + l16)*NL + kt + quad*8;
            const short8 vh0 = *(const short8*)(Vth + vg);
            const short8 vh1 = *(const short8*)(Vth + vg + 32);
            #pragma unroll
            for (int mt=0; mt<2; ++mt) {
                f32x4 a = o[mt][dnt];
                a = MFMA16(fp[mt][0], vh0, a);
                a = MFMA16(fp[mt][1], vh1, a);
                o[mt][dnt] = a;
            }
        }
    }

    // ---- reduce ls within wave (keys split over quads and the r lanes) ----
    float ls[2];
    #pragma unroll
    for (int mt=0; mt<2; ++mt) {
        float t = (ls4[mt][0] + ls4[mt][1]) + (ls4[mt][2] + ls4[mt][3]);
        t += __shfl_xor(t, 16);
        t += __shfl_xor(t, 32);
        ls[mt] = t;             // per-query sum, indexed by l16, replicated
    }

    // ---- cross-half combine: kh=1 dumps partials, kh=0 adds ----
    if (kh == 1) {
        #pragma unroll
        for (int mt=0; mt<2; ++mt) {
            if (quad == 0) sLs[qg][mt*16 + l16] = ls[mt];
            #pragma unroll
            for (int r=0; r<4; ++r) {
                const int row = mt*16 + quad*4 + r;
                #pragma unroll
                for (int dnt=0; dnt<4; ++dnt)
                    sO[qg][row*66 + dnt*16 + l16] = o[mt][dnt][r];
            }
        }
    }
    __syncthreads();
    if (kh == 0) {
        #pragma unroll
        for (int mt=0; mt<2; ++mt) {
            ls[mt] += sLs[qg][mt*16 + l16];
            #pragma unroll
            for (int r=0; r<4; ++r) {
                const int row = mt*16 + quad*4 + r;
                #pragma unroll
                for (int dnt=0; dnt<4; ++dnt)
                    o[mt][dnt][r] += sO[qg][row*66 + dnt*16 + l16];
            }
        }

        // ---- epilogue: O rows = quad*4+r; fetch ls from matching l16 lane ----
        const int bb = bh >> 4, hh = bh & 15;
        #pragma unroll
        for (int mt=0; mt<2; ++mt)
            #pragma unroll
            for (int r=0; r<4; ++r) {
                const float lsv = __int_as_float(__builtin_amdgcn_ds_bpermute(
                    (quad*4 + r) << 2, __float_as_int(ls[mt])));
                const float inv = 1.0f / lsv;
                const int row = q0 + mt*16 + quad*4 + r;
                const size_t ob = (((size_t)(bb*NL + row)) << 10) + (hh << 6);
                #pragma unroll
                for (int dnt=0; dnt<4; ++dnt) {
                    const float val = o[mt][dnt][r] * inv;
                    const ushort_t h = f2bf(val);
                    AOh[ob + dnt*16 + l16] = h;
                    AOl[ob + dnt*16 + l16] = f2bf(val - bf2f(h));
                }
            }
    }
}

extern "C" void kernel_launch(void* const* d_in, const int* in_sizes, int n_in,
                              void* d_out, int out_size, void* d_ws, size_t ws_size,
                              hipStream_t stream)
{
    const float* x     = (const float*)d_in[0];
    const float* Wqkv  = (const float*)d_in[1];
    const float* bqkv  = (const float*)d_in[2];
    const float* Wproj = (const float*)d_in[3];
    const float* bproj = (const float*)d_in[4];
    const int*   isg   = (const int*)d_in[5];
    float* out = (float*)d_out;
    char* base = (char*)d_ws;

    const size_t MB = 1024*1024;
    ushort_t* Qh  = (ushort_t*)(base);
    ushort_t* Kh  = (ushort_t*)(base + 16*MB);
    ushort_t* Vth = (ushort_t*)(base + 32*MB);
    ushort_t* xh  = (ushort_t*)(base + 48*MB);
    ushort_t* xl  = (ushort_t*)(base + 56*MB);
    ushort_t* AOh = xh;                       // alias: xh dead after gemm1
    ushort_t* AOl = xl;
    ushort_t* Wqh = (ushort_t*)(base + 64*MB);
    ushort_t* Wql = (ushort_t*)(base + 64*MB + 6291456);
    ushort_t* Wph = (ushort_t*)(base + 76*MB);
    ushort_t* Wpl = (ushort_t*)(base + 76*MB + 2097152);
    float*    tcs = (float*)(base + 80*MB);          // 32*2048 f32
    float*    tsn = (float*)(base + 80*MB + 262144);

    split_hl<<<4096, 256, 0, stream>>>(x, xh, xl);
    split_hl<<<3072, 256, 0, stream>>>(Wqkv, Wqh, Wql);
    split_hl<<<1024, 256, 0, stream>>>(Wproj, Wph, Wpl);
    rope_tab<<<256, 256, 0, stream>>>(tcs, tsn);

    gemm_hl<0><<<dim3(3*NDIM/128, NM/128), 256, 0, stream>>>(
        xh, xl, Wqh, Wql, bqkv, nullptr,
        Qh, Kh, Vth, tcs, tsn);

    attn_mfma<<<NB*NH*(NL/64), 256, 0, stream>>>(
        Qh, Kh, Vth, AOh, AOl, isg);

    gemm_hl<1><<<dim3(NDIM/128, NM/128), 256, 0, stream>>>(
        AOh, AOl, Wph, Wpl, bproj, out,
        nullptr, nullptr, nullptr, nullptr, nullptr);
}